// Round 8
// baseline (353.380 us; speedup 1.0000x reference)
//
#include <hip/hip_runtime.h>
#include <hip/hip_bf16.h>

#define L_SEQ 4096
#define HID 1024
#define NH 4
#define DH 256
#define CK 64
#define BL_TOT 8192   // B*L

typedef short v8s __attribute__((ext_vector_type(8)));
typedef unsigned short v8u __attribute__((ext_vector_type(8)));
typedef unsigned short v4us __attribute__((ext_vector_type(4)));
typedef float v4f __attribute__((ext_vector_type(4)));

typedef __attribute__((address_space(1))) const void* as1cv;
typedef __attribute__((address_space(3))) void* as3v;

__device__ __forceinline__ unsigned short f2bu(float f) {
    __hip_bfloat16 h = __float2bfloat16(f);
    return *(unsigned short*)&h;
}
__device__ __forceinline__ float bu2f(unsigned short u) {
    __hip_bfloat16 h = *(__hip_bfloat16*)&u;
    return __bfloat162float(h);
}
__device__ __forceinline__ void storec(float* p, float v) { *p = v; }
__device__ __forceinline__ void storec(unsigned short* p, float v) { *p = f2bu(v); }

// ---------------- fused: all-weight f32->bf16 cvt  +  beta/x-bf16 pass ----------------
// blocks [0,1024): weight convert (4 matrices, grid-stride)
// blocks [1024,3072): beta = sigmoid(x @ Wbeta^T) wave-per-row + x -> bf16
__global__ __launch_bounds__(256) void prep_kernel(const float* __restrict__ s0, const float* __restrict__ s1,
                                                   const float* __restrict__ s2, const float* __restrict__ s3,
                                                   unsigned short* __restrict__ d0, unsigned short* __restrict__ d1,
                                                   unsigned short* __restrict__ d2, unsigned short* __restrict__ d3,
                                                   const float* __restrict__ x, const float* __restrict__ Wb,
                                                   float* __restrict__ betaB, unsigned short* __restrict__ xh) {
    const int bid = blockIdx.x;
    const int tid = threadIdx.x;
    if (bid < 1024) {
        const int m = bid >> 8;
        const float* s = m == 0 ? s0 : m == 1 ? s1 : m == 2 ? s2 : s3;
        unsigned short* d = m == 0 ? d0 : m == 1 ? d1 : m == 2 ? d2 : d3;
        int i = (bid & 255) * 256 + tid;
        for (; i < HID * HID; i += 65536) d[i] = f2bu(s[i]);
        return;
    }
    const int t = (bid - 1024) * 4 + (tid >> 6);
    const int lane = tid & 63;
    const float* xr = x + (size_t)t * HID;
    float s[4] = {0.f, 0.f, 0.f, 0.f};
    v4f xv[4];
#pragma unroll
    for (int c = 0; c < 4; ++c) {
        const int i4 = c * 256 + lane * 4;
        xv[c] = *(const v4f*)(xr + i4);
        v4us xp;
#pragma unroll
        for (int i = 0; i < 4; ++i) xp[i] = f2bu(xv[c][i]);
        *(v4us*)&xh[(size_t)t * HID + i4] = xp;
    }
#pragma unroll
    for (int h = 0; h < 4; ++h)
#pragma unroll
        for (int c = 0; c < 4; ++c) {
            v4f wv = *(const v4f*)(Wb + (size_t)h * HID + c * 256 + lane * 4);
            s[h] += xv[c][0] * wv[0] + xv[c][1] * wv[1] + xv[c][2] * wv[2] + xv[c][3] * wv[3];
        }
#pragma unroll
    for (int off = 32; off; off >>= 1)
#pragma unroll
        for (int h = 0; h < 4; ++h) s[h] += __shfl_xor(s[h], off);
    if (lane < 4) betaB[(size_t)t * 4 + lane] = 1.f / (1.f + expf(-s[lane]));
}

// ---------------- MFMA bf16 GEMM: C[M,N] = A[M,K] * B[N,K]^T ----------------
// 128^2 tile, BK=64, global_load_lds width=16, both-sides XOR swizzle (conflict-free).
// 2D grid, m fastest: consecutive blocks share one B-panel (measured-best L2 behavior).
template <typename OT>
__global__ __launch_bounds__(256) void gemm_mfma(const unsigned short* __restrict__ Ah,
                                                 const unsigned short* __restrict__ Bh,
                                                 OT* __restrict__ C, int M, int N, int K) {
    __shared__ unsigned short AsH[128 * 64];
    __shared__ unsigned short BsH[128 * 64];
    const int tid = threadIdx.x;
    const int wave = tid >> 6, lane = tid & 63;
    const int quad = lane >> 4, l16 = lane & 15;
    const int m0 = blockIdx.x * 128, n0 = blockIdx.y * 128;
    const int wm = (wave >> 1) * 64, wn = (wave & 1) * 64;

    // staging: one issue = 256 thr * 16 B = 4 KB = 32 rows * 128 B; 4 issues per 128-row tile
    const int srow = wave * 8 + (lane >> 3);              // 0..31 within issue stripe
    const int scol = (((lane & 7) ^ (lane >> 3)) * 8);    // pre-swizzled source chunk (shorts)
    const unsigned short* Ag = Ah + (size_t)(m0 + srow) * K + scol;
    const unsigned short* Bg = Bh + (size_t)(n0 + srow) * K + scol;
    char* lA = (char*)AsH;
    char* lB = (char*)BsH;
    const int lbase = wave * 1024;

    v4f acc[4][4];
#pragma unroll
    for (int a = 0; a < 4; ++a)
#pragma unroll
        for (int b = 0; b < 4; ++b) { v4f z = {0.f, 0.f, 0.f, 0.f}; acc[a][b] = z; }

    for (int k0 = 0; k0 < K; k0 += 64) {
        __syncthreads();  // previous tile's ds_reads complete
#pragma unroll
        for (int i = 0; i < 4; ++i)
            __builtin_amdgcn_global_load_lds((as1cv)(Ag + (size_t)(i * 32) * K + k0),
                                             (as3v)(lA + i * 4096 + lbase), 16, 0, 0);
#pragma unroll
        for (int i = 0; i < 4; ++i)
            __builtin_amdgcn_global_load_lds((as1cv)(Bg + (size_t)(i * 32) * K + k0),
                                             (as3v)(lB + i * 4096 + lbase), 16, 0, 0);
        __syncthreads();  // drains vmcnt -> LDS tile ready
#pragma unroll
        for (int kk = 0; kk < 2; ++kk) {
            v8s afh[4], bfh[4];
#pragma unroll
            for (int mt = 0; mt < 4; ++mt) {
                const int row = wm + mt * 16 + l16;
                afh[mt] = *(const v8s*)&AsH[row * 64 + (((quad + 4 * kk) ^ (row & 7)) * 8)];
            }
#pragma unroll
            for (int nt = 0; nt < 4; ++nt) {
                const int row = wn + nt * 16 + l16;
                bfh[nt] = *(const v8s*)&BsH[row * 64 + (((quad + 4 * kk) ^ (row & 7)) * 8)];
            }
#pragma unroll
            for (int mt = 0; mt < 4; ++mt)
#pragma unroll
                for (int nt = 0; nt < 4; ++nt)
                    acc[mt][nt] = __builtin_amdgcn_mfma_f32_16x16x32_bf16(afh[mt], bfh[nt], acc[mt][nt], 0, 0, 0);
        }
    }
#pragma unroll
    for (int mt = 0; mt < 4; ++mt)
#pragma unroll
        for (int nt = 0; nt < 4; ++nt) {
            int row = m0 + wm + mt * 16 + quad * 4;
            int col = n0 + wn + nt * 16 + l16;
#pragma unroll
            for (int r = 0; r < 4; ++r)
                storec(&C[(size_t)(row + r) * N + col], acc[mt][nt][r]);
        }
}

// ---------------- fused: final projection GEMM (out0)  +  Spart reduce (out1) ----------------
#define SNS 8
// blocks [0, 512): 128^2 GEMM blocks, m-fastest (bid & 63 = m-tile, bid >> 6 = n-tile)
// blocks [512, 768): reduce SNS partials -> out1 (8 elems/thread)
__global__ __launch_bounds__(256) void final_kernel(const unsigned short* __restrict__ Ah,
                                                    const unsigned short* __restrict__ Bh,
                                                    float* __restrict__ C,
                                                    const float* __restrict__ Spart,
                                                    float* __restrict__ out1) {
    __shared__ unsigned short AsH[128 * 64];
    __shared__ unsigned short BsH[128 * 64];
    const int bid = blockIdx.x;
    const int tid = threadIdx.x;
    if (bid >= 512) {
        const int base = (bid - 512) * 2048 + tid;
#pragma unroll
        for (int k = 0; k < 8; ++k) {
            const int i = base + k * 256;
            float s = 0.f;
#pragma unroll
            for (int ns = 0; ns < SNS; ++ns) s += Spart[(size_t)ns * (8 * 256 * 256) + i];
            out1[i] = s;
        }
        return;
    }
    const int N = HID, K = HID;
    const int wave = tid >> 6, lane = tid & 63;
    const int quad = lane >> 4, l16 = lane & 15;
    const int m0 = (bid & 63) * 128, n0 = (bid >> 6) * 128;
    const int wm = (wave >> 1) * 64, wn = (wave & 1) * 64;
    const int srow = wave * 8 + (lane >> 3);
    const int scol = (((lane & 7) ^ (lane >> 3)) * 8);
    const unsigned short* Ag = Ah + (size_t)(m0 + srow) * K + scol;
    const unsigned short* Bg = Bh + (size_t)(n0 + srow) * K + scol;
    char* lA = (char*)AsH;
    char* lB = (char*)BsH;
    const int lbase = wave * 1024;

    v4f acc[4][4];
#pragma unroll
    for (int a = 0; a < 4; ++a)
#pragma unroll
        for (int b = 0; b < 4; ++b) { v4f z = {0.f, 0.f, 0.f, 0.f}; acc[a][b] = z; }

    for (int k0 = 0; k0 < K; k0 += 64) {
        __syncthreads();
#pragma unroll
        for (int i = 0; i < 4; ++i)
            __builtin_amdgcn_global_load_lds((as1cv)(Ag + (size_t)(i * 32) * K + k0),
                                             (as3v)(lA + i * 4096 + lbase), 16, 0, 0);
#pragma unroll
        for (int i = 0; i < 4; ++i)
            __builtin_amdgcn_global_load_lds((as1cv)(Bg + (size_t)(i * 32) * K + k0),
                                             (as3v)(lB + i * 4096 + lbase), 16, 0, 0);
        __syncthreads();
#pragma unroll
        for (int kk = 0; kk < 2; ++kk) {
            v8s afh[4], bfh[4];
#pragma unroll
            for (int mt = 0; mt < 4; ++mt) {
                const int row = wm + mt * 16 + l16;
                afh[mt] = *(const v8s*)&AsH[row * 64 + (((quad + 4 * kk) ^ (row & 7)) * 8)];
            }
#pragma unroll
            for (int nt = 0; nt < 4; ++nt) {
                const int row = wn + nt * 16 + l16;
                bfh[nt] = *(const v8s*)&BsH[row * 64 + (((quad + 4 * kk) ^ (row & 7)) * 8)];
            }
#pragma unroll
            for (int mt = 0; mt < 4; ++mt)
#pragma unroll
                for (int nt = 0; nt < 4; ++nt)
                    acc[mt][nt] = __builtin_amdgcn_mfma_f32_16x16x32_bf16(afh[mt], bfh[nt], acc[mt][nt], 0, 0, 0);
        }
    }
#pragma unroll
    for (int mt = 0; mt < 4; ++mt)
#pragma unroll
        for (int nt = 0; nt < 4; ++nt) {
            int row = m0 + wm + mt * 16 + quad * 4;
            int col = n0 + wn + nt * 16 + l16;
#pragma unroll
            for (int r = 0; r < 4; ++r)
                C[(size_t)(row + r) * N + col] = acc[mt][nt][r];
        }
}

// ---------------- causal depthwise conv (KS=4) + silu + silu (+ per-head l2norm) ----------------
// 4 rows per block: 7 tap-rows loaded for 4 outputs (tap reuse in registers).
// Thread owns 4 contiguous channels of head (tid>>6); l2norm = wave shuffle per row.
// path p: 0=V (bf16 out, no norm), 1=K (hi/lo out, norm), 2=Q (bf16 out, norm).
__global__ __launch_bounds__(256) void conv_kernel(const unsigned short* __restrict__ G, int gstride, int pathArg,
                                                   const float* __restrict__ wq, const float* __restrict__ wk,
                                                   const float* __restrict__ wv,
                                                   unsigned short* __restrict__ Vout,
                                                   unsigned short* __restrict__ KhiO, unsigned short* __restrict__ KloO,
                                                   unsigned short* __restrict__ Qout) {
    const int p = pathArg < 0 ? (int)blockIdx.y : pathArg;
    const int yoff = pathArg < 0 ? p * 1024 : 0;
    const float* __restrict__ w = p == 0 ? wv : p == 1 ? wk : wq;
    const int bl0 = blockIdx.x * 4;           // 4 consecutive rows; never straddles a sequence (4096%4==0)
    const int l0 = bl0 & (L_SEQ - 1);
    const int tid = threadIdx.x;
    const int lane = tid & 63;
    const int c4 = (tid >> 6) * 256 + lane * 4;  // 4 contiguous channels in head (tid>>6)
    v4f wrow[4];
#pragma unroll
    for (int cc = 0; cc < 4; ++cc) wrow[cc] = *(const v4f*)&w[(c4 + cc) * 4];
    v4f g[7];
#pragma unroll
    for (int t = 0; t < 7; ++t) {
        v4f gv = {0.f, 0.f, 0.f, 0.f};
        if (l0 - 3 + t >= 0) {
            v4us gu = *(const v4us*)&G[(size_t)(bl0 - 3 + t) * gstride + yoff + c4];
#pragma unroll
            for (int i = 0; i < 4; ++i) gv[i] = bu2f(gu[i]);
        }
        g[t] = gv;
    }
#pragma unroll
    for (int r = 0; r < 4; ++r) {
        float vals[4];
#pragma unroll
        for (int cc = 0; cc < 4; ++cc) {
            float a = g[r][cc] * wrow[cc][0] + g[r + 1][cc] * wrow[cc][1] +
                      g[r + 2][cc] * wrow[cc][2] + g[r + 3][cc] * wrow[cc][3];
            float s1 = a / (1.f + expf(-a));
            vals[cc] = s1 / (1.f + expf(-s1));
        }
        if (p >= 1) {
            float sq = vals[0] * vals[0] + vals[1] * vals[1] + vals[2] * vals[2] + vals[3] * vals[3];
#pragma unroll
            for (int off = 32; off; off >>= 1) sq += __shfl_xor(sq, off);
            float nrm = 1.f / fmaxf(sqrtf(sq), 1e-12f);
#pragma unroll
            for (int cc = 0; cc < 4; ++cc) vals[cc] *= nrm;
        }
        const size_t ob = (size_t)(bl0 + r) * HID + c4;
        if (p == 1) {
            v4us hv, lv;
#pragma unroll
            for (int cc = 0; cc < 4; ++cc) {
                unsigned short h = f2bu(vals[cc]);
                hv[cc] = h;
                lv[cc] = f2bu(vals[cc] - bu2f(h));
            }
            *(v4us*)&KhiO[ob] = hv;
            *(v4us*)&KloO[ob] = lv;
        } else {
            unsigned short* O = p == 0 ? Vout : Qout;
            v4us hv;
#pragma unroll
            for (int cc = 0; cc < 4; ++cc) hv[cc] = f2bu(vals[cc]);
            *(v4us*)&O[ob] = hv;
        }
    }
}

// ---------------- per-chunk per-head gram: G_h = K_h * K_h^T (split-bf16 MFMA) ----------------
__global__ __launch_bounds__(256) void gram_kernel(const unsigned short* __restrict__ Khi,
                                                   const unsigned short* __restrict__ Klo,
                                                   float* __restrict__ Gg) {
    const int chunk = blockIdx.x;
    const int h = blockIdx.y;
    const int tid = threadIdx.x;
    const int wave = tid >> 6, lane = tid & 63;
    const int quad = lane >> 4, l16 = lane & 15;
    __shared__ unsigned short Hs[64 * 264];
    __shared__ unsigned short Ls[64 * 264];
    const int l0 = chunk * 64;
    const int cb = h * 256;
#pragma unroll
    for (int p = 0; p < 8; ++p) {
        int row = p * 8 + (tid >> 5);
        int col = (tid & 31) * 8;
        v8u hv = *(const v8u*)(Khi + (size_t)(l0 + row) * HID + cb + col);
        v8u lv = *(const v8u*)(Klo + (size_t)(l0 + row) * HID + cb + col);
        *(v8u*)&Hs[row * 264 + col] = hv;
        *(v8u*)&Ls[row * 264 + col] = lv;
    }
    __syncthreads();
    const int wm = wave * 16;
    v4f acc[4];
#pragma unroll
    for (int nt = 0; nt < 4; ++nt) { v4f z = {0.f, 0.f, 0.f, 0.f}; acc[nt] = z; }
#pragma unroll
    for (int ks = 0; ks < 8; ++ks) {
        v8s ah = *(const v8s*)&Hs[(wm + l16) * 264 + ks * 32 + quad * 8];
        v8s al = *(const v8s*)&Ls[(wm + l16) * 264 + ks * 32 + quad * 8];
#pragma unroll
        for (int nt = 0; nt < 4; ++nt) {
            v8s bh = *(const v8s*)&Hs[(nt * 16 + l16) * 264 + ks * 32 + quad * 8];
            v8s bl = *(const v8s*)&Ls[(nt * 16 + l16) * 264 + ks * 32 + quad * 8];
            acc[nt] = __builtin_amdgcn_mfma_f32_16x16x32_bf16(ah, bh, acc[nt], 0, 0, 0);
            acc[nt] = __builtin_amdgcn_mfma_f32_16x16x32_bf16(ah, bl, acc[nt], 0, 0, 0);
            acc[nt] = __builtin_amdgcn_mfma_f32_16x16x32_bf16(al, bh, acc[nt], 0, 0, 0);
        }
    }
    float* og = Gg + ((size_t)chunk * 4 + h) * 4096;
#pragma unroll
    for (int nt = 0; nt < 4; ++nt)
#pragma unroll
        for (int r = 0; r < 4; ++r)
            og[(wm + quad * 4 + r) * 64 + nt * 16 + l16] = acc[nt][r];
}

// ---------------- T recurrence per chunk via nilpotent doubling + MFMA ----------------
// T_final = 3*(I-A)^{-1} - 2I, A = -tril(beta*gram, -1); (I-A)^{-1} = prod (I + A^(2^k)).
__global__ __launch_bounds__(256) void trec_kernel(const float* __restrict__ Gg,
                                                   const float* __restrict__ betaB,
                                                   float* __restrict__ Tg) {
    const int chunk = blockIdx.x;
    const int tid = threadIdx.x;
    const int wave = tid >> 6, lane = tid & 63;
    const int quad = lane >> 4, l16 = lane & 15;
    const int wm = wave * 16;
    __shared__ unsigned short BhR[64 * 72], BlR[64 * 72];  // B rows   [i][j]
    __shared__ unsigned short BhT[64 * 72], BlT[64 * 72];  // B^T rows [j][i]
    __shared__ unsigned short PhR[64 * 72], PlR[64 * 72];  // P rows   [i][j]
    __shared__ float Pf[64 * 73];                          // P master copy (f32)
    __shared__ float betS[256];
    betS[tid] = betaB[(size_t)chunk * 256 + tid];
    __syncthreads();
    const float* gg = Gg + (size_t)chunk * 4 * 4096;
#pragma unroll
    for (int s = 0; s < 16; ++s) {
        int idx = tid + 256 * s;
        int i = idx >> 6, j = idx & 63;
        float a = 0.f;
        if (i > j) {
            a = -(betS[i * 4 + 0] * gg[idx] + betS[i * 4 + 1] * gg[4096 + idx] +
                  betS[i * 4 + 2] * gg[2 * 4096 + idx] + betS[i * 4 + 3] * gg[3 * 4096 + idx]);
        }
        unsigned short ah = f2bu(a);
        unsigned short al = f2bu(a - bu2f(ah));
        BhR[i * 72 + j] = ah;
        BlR[i * 72 + j] = al;
        BhT[j * 72 + i] = ah;
        BlT[j * 72 + i] = al;
        float p = (i == j) ? 1.f : 0.f;
        Pf[i * 73 + j] = p;
        PhR[i * 72 + j] = f2bu(p);
        PlR[i * 72 + j] = 0;
    }
    __syncthreads();

    for (int st = 0; st < 6; ++st) {
        v8s aBh[2], aBl[2], aPh[2], aPl[2];
        v8s bTh[2][4], bTl[2][4];
#pragma unroll
        for (int kk = 0; kk < 2; ++kk) {
            aBh[kk] = *(const v8s*)&BhR[(wm + l16) * 72 + kk * 32 + quad * 8];
            aBl[kk] = *(const v8s*)&BlR[(wm + l16) * 72 + kk * 32 + quad * 8];
            aPh[kk] = *(const v8s*)&PhR[(wm + l16) * 72 + kk * 32 + quad * 8];
            aPl[kk] = *(const v8s*)&PlR[(wm + l16) * 72 + kk * 32 + quad * 8];
#pragma unroll
            for (int nt = 0; nt < 4; ++nt) {
                bTh[kk][nt] = *(const v8s*)&BhT[(nt * 16 + l16) * 72 + kk * 32 + quad * 8];
                bTl[kk][nt] = *(const v8s*)&BlT[(nt * 16 + l16) * 72 + kk * 32 + quad * 8];
            }
        }
        v4f accP[4], accB[4];
#pragma unroll
        for (int nt = 0; nt < 4; ++nt) {
#pragma unroll
            for (int r = 0; r < 4; ++r)
                accP[nt][r] = Pf[(wm + quad * 4 + r) * 73 + nt * 16 + l16];
            v4f z = {0.f, 0.f, 0.f, 0.f};
            accB[nt] = z;
        }
        __syncthreads();  // all reads done before anyone writes
#pragma unroll
        for (int kk = 0; kk < 2; ++kk)
#pragma unroll
            for (int nt = 0; nt < 4; ++nt) {
                accP[nt] = __builtin_amdgcn_mfma_f32_16x16x32_bf16(aPh[kk], bTh[kk][nt], accP[nt], 0, 0, 0);
                accP[nt] = __builtin_amdgcn_mfma_f32_16x16x32_bf16(aPh[kk], bTl[kk][nt], accP[nt], 0, 0, 0);
                accP[nt] = __builtin_amdgcn_mfma_f32_16x16x32_bf16(aPl[kk], bTh[kk][nt], accP[nt], 0, 0, 0);
            }
        if (st < 5) {
#pragma unroll
            for (int kk = 0; kk < 2; ++kk)
#pragma unroll
                for (int nt = 0; nt < 4; ++nt) {
                    accB[nt] = __builtin_amdgcn_mfma_f32_16x16x32_bf16(aBh[kk], bTh[kk][nt], accB[nt], 0, 0, 0);
                    accB[nt] = __builtin_amdgcn_mfma_f32_16x16x32_bf16(aBh[kk], bTl[kk][nt], accB[nt], 0, 0, 0);
                    accB[nt] = __builtin_amdgcn_mfma_f32_16x16x32_bf16(aBl[kk], bTh[kk][nt], accB[nt], 0, 0, 0);
                }
        }
#pragma unroll
        for (int nt = 0; nt < 4; ++nt)
#pragma unroll
            for (int r = 0; r < 4; ++r) {
                int row = wm + quad * 4 + r;
                int col = nt * 16 + l16;
                float pv = accP[nt][r];
                Pf[row * 73 + col] = pv;
                unsigned short ph = f2bu(pv);
                PhR[row * 72 + col] = ph;
                PlR[row * 72 + col] = f2bu(pv - bu2f(ph));
                if (st < 5) {
                    float bv = accB[nt][r];
                    unsigned short bh2 = f2bu(bv);
                    unsigned short bl2 = f2bu(bv - bu2f(bh2));
                    BhR[row * 72 + col] = bh2;
                    BlR[row * 72 + col] = bl2;
                    BhT[col * 72 + row] = bh2;
                    BlT[col * 72 + row] = bl2;
                }
            }
        __syncthreads();
    }
#pragma unroll
    for (int s = 0; s < 16; ++s) {
        int idx = tid + 256 * s;
        int i = idx >> 6, j = idx & 63;
        float t = (i == j) ? 1.f : 3.f * Pf[i * 73 + j];
        Tg[(size_t)chunk * 4096 + idx] = t;
    }
}

// ---------------- W = T'·K, U = T'·V via MFMA (T' = T·diag(beta)); fused kw/ku ----------------
// v2: T' fragments built in-register straight from global Tg (f32x8 per-lane loads, x beta,
// split hi/lo) — removes the Th/Tl LDS staging pass (LDS 55.6 -> 37.1 KB, 2 -> 3-4 blocks/CU).
// chunk on the slow grid axis (z) so the 8 blocks sharing Tg[chunk] are temporally adjacent.
__global__ __launch_bounds__(256) void wu_mfma_kernel(const float* __restrict__ Tg,
                                                      const unsigned short* __restrict__ Khi,
                                                      const unsigned short* __restrict__ Vhi,
                                                      const float* __restrict__ betaB,
                                                      unsigned short* __restrict__ Wb,
                                                      unsigned short* __restrict__ Ub,
                                                      float* __restrict__ kw, float* __restrict__ ku) {
    const int h = blockIdx.x;      // 4
    const int half = blockIdx.y;   // 2
    const int chunk = blockIdx.z;  // 128
    const int tid = threadIdx.x;
    const int wave = tid >> 6, lane = tid & 63;
    const int quad = lane >> 4, l16 = lane & 15;
    const size_t l0 = (size_t)chunk * 64;
    const int f0 = h * 256 + half * 128;
    __shared__ unsigned short KT[128 * 72], VT[128 * 72];
    __shared__ float betS[64];
    if (tid < 64) betS[tid] = betaB[(l0 + tid) * 4 + h];
    __syncthreads();

    // T' fragments in-register: ah/al[k0][mt], elements j = k0*32 + quad*8 + i
    v8s ahf[2][4], alf[2][4];
#pragma unroll
    for (int kk = 0; kk < 2; ++kk) {
        float bj[8];
#pragma unroll
        for (int i = 0; i < 8; ++i) bj[i] = betS[kk * 32 + quad * 8 + i];
#pragma unroll
        for (int mt = 0; mt < 4; ++mt) {
            const float* trow = Tg + (size_t)chunk * 4096 + (size_t)(mt * 16 + l16) * 64 + kk * 32 + quad * 8;
            v4f t0 = *(const v4f*)trow;
            v4f t1 = *(const v4f*)(trow + 4);
            v8s h8, l8;
#pragma unroll
            for (int i = 0; i < 4; ++i) {
                float v = t0[i] * bj[i];
                unsigned short hv = f2bu(v);
                h8[i] = (short)hv;
                l8[i] = (short)f2bu(v - bu2f(hv));
                float v2 = t1[i] * bj[4 + i];
                unsigned short hv2 = f2bu(v2);
                h8[4 + i] = (short)hv2;
                l8[4 + i] = (short)f2bu(v2 - bu2f(hv2));
            }
            ahf[kk][mt] = h8;
            alf[kk][mt] = l8;
        }
    }

#pragma unroll
    for (int pass = 0; pass < 4; ++pass) {
        int j = pass * 16 + (tid >> 4);
        int fc = (tid & 15) * 8;
        v8u kv = *(const v8u*)(Khi + (l0 + j) * HID + f0 + fc);
        v8u vv = *(const v8u*)(Vhi + (l0 + j) * HID + f0 + fc);
#pragma unroll
        for (int i = 0; i < 8; ++i) {
            KT[(fc + i) * 72 + j] = kv[i];
            VT[(fc + i) * 72 + j] = vv[i];
        }
    }
    __syncthreads();

    const int nf = wave * 32;
    const int bb = chunk >> 6, nn = chunk & 63;
    const size_t obase = (((size_t)bb * 4 + h) * 64 + nn) * 256 + half * 128;

#pragma unroll
    for (int phase = 0; phase < 2; ++phase) {
        const unsigned short* BT = phase ? VT : KT;
        v4f acc[4][2];
#pragma unroll
        for (int mt = 0; mt < 4; ++mt)
#pragma unroll
            for (int nt = 0; nt < 2; ++nt) { v4f z = {0.f, 0.f, 0.f, 0.f}; acc[mt][nt] = z; }
#pragma unroll
        for (int kk = 0; kk < 2; ++kk) {
            const int k0 = kk * 32;
            v8s bf[2];
#pragma unroll
            for (int nt = 0; nt < 2; ++nt)
                bf[nt] = *(const v8s*)&BT[(nf + nt * 16 + l16) * 72 + k0 + quad * 8];
#pragma unroll
            for (int mt = 0; mt < 4; ++mt)
#pragma unroll
                for (int nt = 0; nt < 2; ++nt) {
                    acc[mt][nt] = __builtin_amdgcn_mfma_f32_16x16x32_bf16(ahf[kk][mt], bf[nt], acc[mt][nt], 0, 0, 0);
                    acc[mt][nt] = __builtin_amdgcn_mfma_f32_16x16x32_bf16(alf[kk][mt], bf[nt], acc[mt][nt], 0, 0, 0);
                }
        }
        unsigned short* Out = phase ? Ub : Wb;
        float* kk2 = phase ? ku : kw;
#pragma unroll
        for (int nt = 0; nt < 2; ++nt) {
            const int fl = nf + nt * 16 + l16;
            float dot = 0.f;
#pragma unroll
            for (int mt = 0; mt < 4; ++mt)
#pragma unroll
                for (int r = 0; r < 4; ++r) {
                    const int c = mt * 16 + quad * 4 + r;
                    float wv = acc[mt][nt][r];
                    Out[(l0 + c) * HID + f0 + fl] = f2bu(wv);
                    dot += bu2f(KT[fl * 72 + c]) * wv;
                }
            dot += __shfl_xor(dot, 16);
            dot += __shfl_xor(dot, 32);
            if (quad == 0) kk2[obase + fl] = dot;
        }
    }
}

// ---------------- diagonal scan over chunks (load-pipelined serial loop) ----------------
__global__ __launch_bounds__(256) void scan_kernel(const float* __restrict__ kw,
                                                   const float* __restrict__ ku,
                                                   float* __restrict__ dsA) {
    const int bh = blockIdx.x;
    size_t idx = (size_t)bh * 64 * 256 + threadIdx.x;
    float ds = 0.f;
    float kwc = kw[idx], kuc = ku[idx];
    for (int n = 0; n < 64; ++n) {
        float kwn = 0.f, kun = 0.f;
        if (n < 63) {  // prefetch next chunk's coeffs off the dependent chain
            kwn = kw[idx + 256];
            kun = ku[idx + 256];
        }
        dsA[idx] = ds;
        ds = ds * (1.f - kwc) + kuc;
        kwc = kwn;
        kuc = kun;
        idx += 256;
    }
}

// ---------------- o = q*ds + [c<=b]*A*(u - w*ds); fused RMSNorm + bf16 cast (wave-per-row) ----------------
__global__ __launch_bounds__(256) void o_kernel(const unsigned short* __restrict__ Qb,
                                                const unsigned short* __restrict__ Khi,
                                                const unsigned short* __restrict__ Wb,
                                                const unsigned short* __restrict__ Ub,
                                                const float* __restrict__ dsA,
                                                const float* __restrict__ rmsw,
                                                unsigned short* __restrict__ ob,
                                                unsigned short* __restrict__ ub) {
    const int r = blockIdx.x * 4 + (threadIdx.x >> 6);
    const int lane = threadIdx.x & 63;
    const int b = r >> 12, l = r & (L_SEQ - 1);
    const int n = l >> 6, cpos = l & 63;
    const size_t rowb = (size_t)r * HID;
    const bool doA = (cpos <= b);
    float qv[4][4];
    v4f dsv[4];
    float As = 0.f;
#pragma unroll
    for (int hh = 0; hh < 4; ++hh) {
        const int c4 = hh * 256 + lane * 4;
        dsv[hh] = *(const v4f*)&dsA[(((size_t)b * 4 + hh) * 64 + n) * 256 + lane * 4];
        v4us qu = *(const v4us*)&Qb[rowb + c4];
#pragma unroll
        for (int i = 0; i < 4; ++i) qv[hh][i] = bu2f(qu[i]);
        if (doA) {
            v4us kq = *(const v4us*)&Khi[rowb + c4];
#pragma unroll
            for (int i = 0; i < 4; ++i) As += qv[hh][i] * bu2f(kq[i]);
        }
    }
    float Aval = 0.f;
    if (doA) {
#pragma unroll
        for (int off = 32; off; off >>= 1) As += __shfl_xor(As, off);
        Aval = As;
    }
    float ss = 0.f;
    float ov[4][4];
#pragma unroll
    for (int hh = 0; hh < 4; ++hh) {
        const int c4 = hh * 256 + lane * 4;
        v4us uu = *(const v4us*)&Ub[rowb + c4];
        v4us wu4 = *(const v4us*)&Wb[rowb + c4];
        v4us up;
#pragma unroll
        for (int i = 0; i < 4; ++i) {
            float u = bu2f(uu[i]) - bu2f(wu4[i]) * dsv[hh][i];
            up[i] = f2bu(u);
            float o = qv[hh][i] * dsv[hh][i];
            if (doA) o += Aval * u;
            ov[hh][i] = o;
            ss += o * o;
        }
        *(v4us*)&ub[rowb + c4] = up;
    }
#pragma unroll
    for (int off = 32; off; off >>= 1) ss += __shfl_xor(ss, off);
    float scale = rsqrtf(ss * (1.f / 1024.f) + 1e-5f);
#pragma unroll
    for (int hh = 0; hh < 4; ++hh) {
        const int c4 = hh * 256 + lane * 4;
        v4f rw = *(const v4f*)&rmsw[c4];
        v4us op;
#pragma unroll
        for (int i = 0; i < 4; ++i) op[i] = f2bu(ov[hh][i] * scale * rw[i]);
        *(v4us*)&ob[rowb + c4] = op;
    }
}

// ---------------- state S = K^T u'  via MFMA (n-split partials) ----------------
__global__ __launch_bounds__(256) void s_mfma_kernel(const unsigned short* __restrict__ Khi,
                                                     const unsigned short* __restrict__ Ub,
                                                     float* __restrict__ Spart) {
    const int bh = blockIdx.x;
    const int b = bh >> 2, h = bh & 3;
    const int dt = blockIdx.y;
    const int et = blockIdx.z & 1;
    const int ns = blockIdx.z >> 1;
    const int tid = threadIdx.x;
    const int wave = tid >> 6, lane = tid & 63;
    const int quad = lane >> 4, l16 = lane & 15;
    const int wm = (wave >> 1) * 64, wn = (wave & 1) * 64;
    __shared__ unsigned short Kt[128 * 40];
    __shared__ unsigned short Ut[128 * 40];
    const int cc = tid >> 3;
    const int dcol = (tid & 7) * 16;
    const size_t rowbase = (size_t)b * 4096 + (size_t)ns * 512;
    const int ck = h * 256 + dt * 128;
    const int ce = h * 256 + et * 128;
    v4f acc[4][4];
#pragma unroll
    for (int a = 0; a < 4; ++a)
#pragma unroll
        for (int c2 = 0; c2 < 4; ++c2) { v4f z = {0.f, 0.f, 0.f, 0.f}; acc[a][c2] = z; }

    for (int kt = 0; kt < 16; ++kt) {
        size_t row = rowbase + kt * 32 + cc;
        v8u k0 = *(const v8u*)(Khi + row * HID + ck + dcol);
        v8u k1 = *(const v8u*)(Khi + row * HID + ck + dcol + 8);
        v8u u0 = *(const v8u*)(Ub + row * HID + ce + dcol);
        v8u u1 = *(const v8u*)(Ub + row * HID + ce + dcol + 8);
        __syncthreads();
#pragma unroll
        for (int j = 0; j < 8; ++j) {
            Kt[(dcol + j) * 40 + cc] = k0[j];
            Kt[(dcol + 8 + j) * 40 + cc] = k1[j];
            Ut[(dcol + j) * 40 + cc] = u0[j];
            Ut[(dcol + 8 + j) * 40 + cc] = u1[j];
        }
        __syncthreads();
        v8s af[4], bf[4];
#pragma unroll
        for (int mt = 0; mt < 4; ++mt) af[mt] = *(const v8s*)&Kt[(wm + mt * 16 + l16) * 40 + quad * 8];
#pragma unroll
        for (int nt = 0; nt < 4; ++nt) bf[nt] = *(const v8s*)&Ut[(wn + nt * 16 + l16) * 40 + quad * 8];
#pragma unroll
        for (int mt = 0; mt < 4; ++mt)
#pragma unroll
            for (int nt = 0; nt < 4; ++nt)
                acc[mt][nt] = __builtin_amdgcn_mfma_f32_16x16x32_bf16(af[mt], bf[nt], acc[mt][nt], 0, 0, 0);
    }
    float* out = Spart + (size_t)ns * (8 * 256 * 256);
#pragma unroll
    for (int mt = 0; mt < 4; ++mt)
#pragma unroll
        for (int nt = 0; nt < 4; ++nt) {
            int row = dt * 128 + wm + mt * 16 + quad * 4;
            int col = et * 128 + wn + nt * 16 + l16;
#pragma unroll
            for (int r = 0; r < 4; ++r)
                out[((size_t)bh * 256 + row + r) * 256 + col] = acc[mt][nt][r];
        }
}

extern "C" void kernel_launch(void* const* d_in, const int* in_sizes, int n_in,
                              void* d_out, int out_size, void* d_ws, size_t ws_size,
                              hipStream_t stream) {
    const float* x     = (const float*)d_in[0];
    const float* Wq    = (const float*)d_in[1];
    const float* Wk    = (const float*)d_in[2];
    const float* Wv    = (const float*)d_in[3];
    const float* convq = (const float*)d_in[4];
    const float* convk = (const float*)d_in[5];
    const float* convv = (const float*)d_in[6];
    const float* Wbeta = (const float*)d_in[7];
    const float* rmsw  = (const float*)d_in[8];
    const float* Wo    = (const float*)d_in[9];

    // ---- workspace map (aliases documented) ----
    char* ws = (char*)d_ws;
    size_t off = 0;
    auto alloc = [&](size_t bytes) {
        char* p = ws + off;
        off += (bytes + 255) & ~(size_t)255;
        return (void*)p;
    };
    const size_t MM = (size_t)HID * HID;
    unsigned short* xhi   = (unsigned short*)alloc((size_t)BL_TOT * HID * 2);  // later Qm/ob
    unsigned short* Khi   = (unsigned short*)alloc((size_t)BL_TOT * HID * 2);  // conv_k -> s_mfma
    unsigned short* wbQKV = (unsigned short*)alloc(3 * MM * 2);                // [V|K|Q] packed
    unsigned short* wbO   = (unsigned short*)alloc(MM * 2);
    unsigned short* Vhi   = (unsigned short*)alloc((size_t)BL_TOT * HID * 2);
    unsigned short* Wb16  = (unsigned short*)alloc((size_t)BL_TOT * HID * 2);
    unsigned short* Ub16  = (unsigned short*)alloc((size_t)BL_TOT * HID * 2);
    float* Tg    = (float*)alloc((size_t)128 * 4096 * 4);
    float* betaB = (float*)alloc((size_t)BL_TOT * 4 * 4);
    float* kwB   = (float*)alloc((size_t)8 * 64 * 256 * 4);
    float* kuB   = (float*)alloc((size_t)8 * 64 * 256 * 4);
    float* dsA   = (float*)alloc((size_t)8 * 64 * 256 * 4);
    // Gt last: bf16 GEMM output. big = 8192x3072 (merged QKV) if workspace allows.
    const size_t gt_big = (size_t)BL_TOT * 3 * HID * 2;
    const size_t gt_small = (size_t)BL_TOT * HID * 2;
    // Spart (16 MB f32) aliases Gt; ensure allocation covers it in either path.
    const size_t spart_bytes = (size_t)SNS * 8 * 256 * 256 * 4;
    const bool big = (off + (gt_big > spart_bytes ? gt_big : spart_bytes)) <= ws_size;
    unsigned short* Gt = (unsigned short*)alloc(big ? (gt_big > spart_bytes ? gt_big : spart_bytes)
                                                    : (gt_small > spart_bytes ? gt_small : spart_bytes));

    unsigned short* Qm = xhi;   // xhi dead after (last) x-GEMM
    unsigned short* ob = Qm;    // q dead after o_kernel reads its own row
    float* Spart = (float*)Gt;  // Gt dead after conv

    float* out0 = (float*)d_out;
    float* out1 = out0 + (size_t)BL_TOT * HID;
    // d_out as pre-final scratch (validated only after launch):
    unsigned short* Klo = (unsigned short*)out0;            // bytes 0..16.78M
    unsigned short* ubf = (unsigned short*)out0 + 8388608;  // bytes 16.78M..33.55M
    float* Gg = out0 + (size_t)4400000;                     // gram scratch; dead before o_kernel

    dim3 blk(256);
    dim3 ggrid(BL_TOT / 128, HID / 128);

    // fused weight-cvt + beta (blocks [0,1024) = wcvt, [1024,3072) = beta)
    prep_kernel<<<3072, blk, 0, stream>>>(Wv, Wk, Wq, Wo, wbQKV, wbQKV + MM, wbQKV + 2 * MM, wbO,
                                          x, Wbeta, betaB, xhi);

    if (big) {
        // one QKV GEMM (N=3072, bf16 out) + one merged conv dispatch
        gemm_mfma<unsigned short><<<dim3(BL_TOT / 128, 3 * HID / 128), blk, 0, stream>>>(
            xhi, wbQKV, Gt, BL_TOT, 3 * HID, HID);
        conv_kernel<<<dim3(BL_TOT / 4, 3), blk, 0, stream>>>(Gt, 3 * HID, -1, convq, convk, convv,
                                                             Vhi, Khi, Klo, Qm);
        gram_kernel<<<dim3(128, 4), blk, 0, stream>>>(Khi, Klo, Gg);
        trec_kernel<<<128, blk, 0, stream>>>(Gg, betaB, Tg);
    } else {
        // sequential fallback (Gt reused; Q GEMM last so Qm alias of xhi stays safe)
        gemm_mfma<unsigned short><<<ggrid, blk, 0, stream>>>(xhi, wbQKV, Gt, BL_TOT, HID, HID);
        conv_kernel<<<dim3(BL_TOT / 4, 1), blk, 0, stream>>>(Gt, HID, 0, convq, convk, convv, Vhi, Khi, Klo, Qm);
        gemm_mfma<unsigned short><<<ggrid, blk, 0, stream>>>(xhi, wbQKV + MM, Gt, BL_TOT, HID, HID);
        conv_kernel<<<dim3(BL_TOT / 4, 1), blk, 0, stream>>>(Gt, HID, 1, convq, convk, convv, Vhi, Khi, Klo, Qm);
        gram_kernel<<<dim3(128, 4), blk, 0, stream>>>(Khi, Klo, Gg);
        trec_kernel<<<128, blk, 0, stream>>>(Gg, betaB, Tg);
        gemm_mfma<unsigned short><<<ggrid, blk, 0, stream>>>(xhi, wbQKV + 2 * MM, Gt, BL_TOT, HID, HID);
        conv_kernel<<<dim3(BL_TOT / 4, 1), blk, 0, stream>>>(Gt, HID, 2, convq, convk, convv, Vhi, Khi, Klo, Qm);
    }

    // chunked delta rule (wu: chunk on slow z-axis for Tg L2 locality)
    wu_mfma_kernel<<<dim3(4, 2, 128), blk, 0, stream>>>(Tg, Khi, Vhi, betaB, Wb16, Ub16, kwB, kuB);
    scan_kernel<<<8, blk, 0, stream>>>(kwB, kuB, dsA);
    o_kernel<<<BL_TOT / 4, blk, 0, stream>>>(Qm, Khi, Wb16, Ub16, dsA, rmsw, ob, ubf);
    s_mfma_kernel<<<dim3(8, 2, 2 * SNS), blk, 0, stream>>>(Khi, ubf, Spart);

    // fused final projection (blocks [0,512)) + Spart reduce -> out1 (blocks [512,768))
    final_kernel<<<768, blk, 0, stream>>>(ob, wbO, out0, Spart, out1);
}

// Round 9
// 345.727 us; speedup vs baseline: 1.0221x; 1.0221x over previous
//
#include <hip/hip_runtime.h>
#include <hip/hip_bf16.h>

#define L_SEQ 4096
#define HID 1024
#define NH 4
#define DH 256
#define CK 64
#define BL_TOT 8192   // B*L

typedef short v8s __attribute__((ext_vector_type(8)));
typedef unsigned short v8u __attribute__((ext_vector_type(8)));
typedef unsigned short v4us __attribute__((ext_vector_type(4)));
typedef float v4f __attribute__((ext_vector_type(4)));

typedef __attribute__((address_space(1))) const void* as1cv;
typedef __attribute__((address_space(3))) void* as3v;

__device__ __forceinline__ unsigned short f2bu(float f) {
    __hip_bfloat16 h = __float2bfloat16(f);
    return *(unsigned short*)&h;
}
__device__ __forceinline__ float bu2f(unsigned short u) {
    __hip_bfloat16 h = *(__hip_bfloat16*)&u;
    return __bfloat162float(h);
}
__device__ __forceinline__ void storec(float* p, float v) { *p = v; }
__device__ __forceinline__ void storec(unsigned short* p, float v) { *p = f2bu(v); }

// ---------------- fused: all-weight f32->bf16 cvt  +  beta/x-bf16 pass ----------------
// blocks [0,1024): weight convert (4 matrices, grid-stride)
// blocks [1024,3072): beta = sigmoid(x @ Wbeta^T) wave-per-row + x -> bf16
__global__ __launch_bounds__(256) void prep_kernel(const float* __restrict__ s0, const float* __restrict__ s1,
                                                   const float* __restrict__ s2, const float* __restrict__ s3,
                                                   unsigned short* __restrict__ d0, unsigned short* __restrict__ d1,
                                                   unsigned short* __restrict__ d2, unsigned short* __restrict__ d3,
                                                   const float* __restrict__ x, const float* __restrict__ Wb,
                                                   float* __restrict__ betaB, unsigned short* __restrict__ xh) {
    const int bid = blockIdx.x;
    const int tid = threadIdx.x;
    if (bid < 1024) {
        const int m = bid >> 8;
        const float* s = m == 0 ? s0 : m == 1 ? s1 : m == 2 ? s2 : s3;
        unsigned short* d = m == 0 ? d0 : m == 1 ? d1 : m == 2 ? d2 : d3;
        int i = (bid & 255) * 256 + tid;
        for (; i < HID * HID; i += 65536) d[i] = f2bu(s[i]);
        return;
    }
    const int t = (bid - 1024) * 4 + (tid >> 6);
    const int lane = tid & 63;
    const float* xr = x + (size_t)t * HID;
    float s[4] = {0.f, 0.f, 0.f, 0.f};
    v4f xv[4];
#pragma unroll
    for (int c = 0; c < 4; ++c) {
        const int i4 = c * 256 + lane * 4;
        xv[c] = *(const v4f*)(xr + i4);
        v4us xp;
#pragma unroll
        for (int i = 0; i < 4; ++i) xp[i] = f2bu(xv[c][i]);
        *(v4us*)&xh[(size_t)t * HID + i4] = xp;
    }
#pragma unroll
    for (int h = 0; h < 4; ++h)
#pragma unroll
        for (int c = 0; c < 4; ++c) {
            v4f wv = *(const v4f*)(Wb + (size_t)h * HID + c * 256 + lane * 4);
            s[h] += xv[c][0] * wv[0] + xv[c][1] * wv[1] + xv[c][2] * wv[2] + xv[c][3] * wv[3];
        }
#pragma unroll
    for (int off = 32; off; off >>= 1)
#pragma unroll
        for (int h = 0; h < 4; ++h) s[h] += __shfl_xor(s[h], off);
    if (lane < 4) betaB[(size_t)t * 4 + lane] = 1.f / (1.f + expf(-s[lane]));
}

// ---------------- MFMA bf16 GEMM: C[M,N] = A[M,K] * B[N,K]^T ----------------
// 128^2 tile, BK=64, global_load_lds width=16, both-sides XOR swizzle (conflict-free).
// 2D grid, m fastest: consecutive blocks share one B-panel (measured-best L2 behavior).
template <typename OT>
__global__ __launch_bounds__(256) void gemm_mfma(const unsigned short* __restrict__ Ah,
                                                 const unsigned short* __restrict__ Bh,
                                                 OT* __restrict__ C, int M, int N, int K) {
    __shared__ unsigned short AsH[128 * 64];
    __shared__ unsigned short BsH[128 * 64];
    const int tid = threadIdx.x;
    const int wave = tid >> 6, lane = tid & 63;
    const int quad = lane >> 4, l16 = lane & 15;
    const int m0 = blockIdx.x * 128, n0 = blockIdx.y * 128;
    const int wm = (wave >> 1) * 64, wn = (wave & 1) * 64;

    // staging: one issue = 256 thr * 16 B = 4 KB = 32 rows * 128 B; 4 issues per 128-row tile
    const int srow = wave * 8 + (lane >> 3);              // 0..31 within issue stripe
    const int scol = (((lane & 7) ^ (lane >> 3)) * 8);    // pre-swizzled source chunk (shorts)
    const unsigned short* Ag = Ah + (size_t)(m0 + srow) * K + scol;
    const unsigned short* Bg = Bh + (size_t)(n0 + srow) * K + scol;
    char* lA = (char*)AsH;
    char* lB = (char*)BsH;
    const int lbase = wave * 1024;

    v4f acc[4][4];
#pragma unroll
    for (int a = 0; a < 4; ++a)
#pragma unroll
        for (int b = 0; b < 4; ++b) { v4f z = {0.f, 0.f, 0.f, 0.f}; acc[a][b] = z; }

    for (int k0 = 0; k0 < K; k0 += 64) {
        __syncthreads();  // previous tile's ds_reads complete
#pragma unroll
        for (int i = 0; i < 4; ++i)
            __builtin_amdgcn_global_load_lds((as1cv)(Ag + (size_t)(i * 32) * K + k0),
                                             (as3v)(lA + i * 4096 + lbase), 16, 0, 0);
#pragma unroll
        for (int i = 0; i < 4; ++i)
            __builtin_amdgcn_global_load_lds((as1cv)(Bg + (size_t)(i * 32) * K + k0),
                                             (as3v)(lB + i * 4096 + lbase), 16, 0, 0);
        __syncthreads();  // drains vmcnt -> LDS tile ready
#pragma unroll
        for (int kk = 0; kk < 2; ++kk) {
            v8s afh[4], bfh[4];
#pragma unroll
            for (int mt = 0; mt < 4; ++mt) {
                const int row = wm + mt * 16 + l16;
                afh[mt] = *(const v8s*)&AsH[row * 64 + (((quad + 4 * kk) ^ (row & 7)) * 8)];
            }
#pragma unroll
            for (int nt = 0; nt < 4; ++nt) {
                const int row = wn + nt * 16 + l16;
                bfh[nt] = *(const v8s*)&BsH[row * 64 + (((quad + 4 * kk) ^ (row & 7)) * 8)];
            }
#pragma unroll
            for (int mt = 0; mt < 4; ++mt)
#pragma unroll
                for (int nt = 0; nt < 4; ++nt)
                    acc[mt][nt] = __builtin_amdgcn_mfma_f32_16x16x32_bf16(afh[mt], bfh[nt], acc[mt][nt], 0, 0, 0);
        }
    }
#pragma unroll
    for (int mt = 0; mt < 4; ++mt)
#pragma unroll
        for (int nt = 0; nt < 4; ++nt) {
            int row = m0 + wm + mt * 16 + quad * 4;
            int col = n0 + wn + nt * 16 + l16;
#pragma unroll
            for (int r = 0; r < 4; ++r)
                storec(&C[(size_t)(row + r) * N + col], acc[mt][nt][r]);
        }
}

// ---------------- fused: final projection GEMM (out0)  +  Spart reduce (out1) ----------------
#define SNS 8
// blocks [0, 512): 128^2 GEMM blocks, m-fastest (bid & 63 = m-tile, bid >> 6 = n-tile)
// blocks [512, 768): reduce SNS partials -> out1 (8 elems/thread)
__global__ __launch_bounds__(256) void final_kernel(const unsigned short* __restrict__ Ah,
                                                    const unsigned short* __restrict__ Bh,
                                                    float* __restrict__ C,
                                                    const float* __restrict__ Spart,
                                                    float* __restrict__ out1) {
    __shared__ unsigned short AsH[128 * 64];
    __shared__ unsigned short BsH[128 * 64];
    const int bid = blockIdx.x;
    const int tid = threadIdx.x;
    if (bid >= 512) {
        const int base = (bid - 512) * 2048 + tid;
#pragma unroll
        for (int k = 0; k < 8; ++k) {
            const int i = base + k * 256;
            float s = 0.f;
#pragma unroll
            for (int ns = 0; ns < SNS; ++ns) s += Spart[(size_t)ns * (8 * 256 * 256) + i];
            out1[i] = s;
        }
        return;
    }
    const int N = HID, K = HID;
    const int wave = tid >> 6, lane = tid & 63;
    const int quad = lane >> 4, l16 = lane & 15;
    const int m0 = (bid & 63) * 128, n0 = (bid >> 6) * 128;
    const int wm = (wave >> 1) * 64, wn = (wave & 1) * 64;
    const int srow = wave * 8 + (lane >> 3);
    const int scol = (((lane & 7) ^ (lane >> 3)) * 8);
    const unsigned short* Ag = Ah + (size_t)(m0 + srow) * K + scol;
    const unsigned short* Bg = Bh + (size_t)(n0 + srow) * K + scol;
    char* lA = (char*)AsH;
    char* lB = (char*)BsH;
    const int lbase = wave * 1024;

    v4f acc[4][4];
#pragma unroll
    for (int a = 0; a < 4; ++a)
#pragma unroll
        for (int b = 0; b < 4; ++b) { v4f z = {0.f, 0.f, 0.f, 0.f}; acc[a][b] = z; }

    for (int k0 = 0; k0 < K; k0 += 64) {
        __syncthreads();
#pragma unroll
        for (int i = 0; i < 4; ++i)
            __builtin_amdgcn_global_load_lds((as1cv)(Ag + (size_t)(i * 32) * K + k0),
                                             (as3v)(lA + i * 4096 + lbase), 16, 0, 0);
#pragma unroll
        for (int i = 0; i < 4; ++i)
            __builtin_amdgcn_global_load_lds((as1cv)(Bg + (size_t)(i * 32) * K + k0),
                                             (as3v)(lB + i * 4096 + lbase), 16, 0, 0);
        __syncthreads();
#pragma unroll
        for (int kk = 0; kk < 2; ++kk) {
            v8s afh[4], bfh[4];
#pragma unroll
            for (int mt = 0; mt < 4; ++mt) {
                const int row = wm + mt * 16 + l16;
                afh[mt] = *(const v8s*)&AsH[row * 64 + (((quad + 4 * kk) ^ (row & 7)) * 8)];
            }
#pragma unroll
            for (int nt = 0; nt < 4; ++nt) {
                const int row = wn + nt * 16 + l16;
                bfh[nt] = *(const v8s*)&BsH[row * 64 + (((quad + 4 * kk) ^ (row & 7)) * 8)];
            }
#pragma unroll
            for (int mt = 0; mt < 4; ++mt)
#pragma unroll
                for (int nt = 0; nt < 4; ++nt)
                    acc[mt][nt] = __builtin_amdgcn_mfma_f32_16x16x32_bf16(afh[mt], bfh[nt], acc[mt][nt], 0, 0, 0);
        }
    }
#pragma unroll
    for (int mt = 0; mt < 4; ++mt)
#pragma unroll
        for (int nt = 0; nt < 4; ++nt) {
            int row = m0 + wm + mt * 16 + quad * 4;
            int col = n0 + wn + nt * 16 + l16;
#pragma unroll
            for (int r = 0; r < 4; ++r)
                C[(size_t)(row + r) * N + col] = acc[mt][nt][r];
        }
}

// ---------------- causal depthwise conv (KS=4) + silu + silu (+ per-head l2norm) ----------------
// 4 rows per block: 7 tap-rows loaded for 4 outputs (tap reuse in registers).
// Thread owns 4 contiguous channels of head (tid>>6); l2norm = wave shuffle per row.
// path p: 0=V (bf16 out, no norm), 1=K (hi/lo out, norm), 2=Q (bf16 out, norm).
__global__ __launch_bounds__(256) void conv_kernel(const unsigned short* __restrict__ G, int gstride, int pathArg,
                                                   const float* __restrict__ wq, const float* __restrict__ wk,
                                                   const float* __restrict__ wv,
                                                   unsigned short* __restrict__ Vout,
                                                   unsigned short* __restrict__ KhiO, unsigned short* __restrict__ KloO,
                                                   unsigned short* __restrict__ Qout) {
    const int p = pathArg < 0 ? (int)blockIdx.y : pathArg;
    const int yoff = pathArg < 0 ? p * 1024 : 0;
    const float* __restrict__ w = p == 0 ? wv : p == 1 ? wk : wq;
    const int bl0 = blockIdx.x * 4;           // 4 consecutive rows; never straddles a sequence (4096%4==0)
    const int l0 = bl0 & (L_SEQ - 1);
    const int tid = threadIdx.x;
    const int lane = tid & 63;
    const int c4 = (tid >> 6) * 256 + lane * 4;  // 4 contiguous channels in head (tid>>6)
    v4f wrow[4];
#pragma unroll
    for (int cc = 0; cc < 4; ++cc) wrow[cc] = *(const v4f*)&w[(c4 + cc) * 4];
    v4f g[7];
#pragma unroll
    for (int t = 0; t < 7; ++t) {
        v4f gv = {0.f, 0.f, 0.f, 0.f};
        if (l0 - 3 + t >= 0) {
            v4us gu = *(const v4us*)&G[(size_t)(bl0 - 3 + t) * gstride + yoff + c4];
#pragma unroll
            for (int i = 0; i < 4; ++i) gv[i] = bu2f(gu[i]);
        }
        g[t] = gv;
    }
#pragma unroll
    for (int r = 0; r < 4; ++r) {
        float vals[4];
#pragma unroll
        for (int cc = 0; cc < 4; ++cc) {
            float a = g[r][cc] * wrow[cc][0] + g[r + 1][cc] * wrow[cc][1] +
                      g[r + 2][cc] * wrow[cc][2] + g[r + 3][cc] * wrow[cc][3];
            float s1 = a / (1.f + expf(-a));
            vals[cc] = s1 / (1.f + expf(-s1));
        }
        if (p >= 1) {
            float sq = vals[0] * vals[0] + vals[1] * vals[1] + vals[2] * vals[2] + vals[3] * vals[3];
#pragma unroll
            for (int off = 32; off; off >>= 1) sq += __shfl_xor(sq, off);
            float nrm = 1.f / fmaxf(sqrtf(sq), 1e-12f);
#pragma unroll
            for (int cc = 0; cc < 4; ++cc) vals[cc] *= nrm;
        }
        const size_t ob = (size_t)(bl0 + r) * HID + c4;
        if (p == 1) {
            v4us hv, lv;
#pragma unroll
            for (int cc = 0; cc < 4; ++cc) {
                unsigned short h = f2bu(vals[cc]);
                hv[cc] = h;
                lv[cc] = f2bu(vals[cc] - bu2f(h));
            }
            *(v4us*)&KhiO[ob] = hv;
            *(v4us*)&KloO[ob] = lv;
        } else {
            unsigned short* O = p == 0 ? Vout : Qout;
            v4us hv;
#pragma unroll
            for (int cc = 0; cc < 4; ++cc) hv[cc] = f2bu(vals[cc]);
            *(v4us*)&O[ob] = hv;
        }
    }
}

// ---------------- per-chunk per-head gram: G_h = K_h * K_h^T (split-bf16 MFMA) ----------------
__global__ __launch_bounds__(256) void gram_kernel(const unsigned short* __restrict__ Khi,
                                                   const unsigned short* __restrict__ Klo,
                                                   float* __restrict__ Gg) {
    const int chunk = blockIdx.x;
    const int h = blockIdx.y;
    const int tid = threadIdx.x;
    const int wave = tid >> 6, lane = tid & 63;
    const int quad = lane >> 4, l16 = lane & 15;
    __shared__ unsigned short Hs[64 * 264];
    __shared__ unsigned short Ls[64 * 264];
    const int l0 = chunk * 64;
    const int cb = h * 256;
#pragma unroll
    for (int p = 0; p < 8; ++p) {
        int row = p * 8 + (tid >> 5);
        int col = (tid & 31) * 8;
        v8u hv = *(const v8u*)(Khi + (size_t)(l0 + row) * HID + cb + col);
        v8u lv = *(const v8u*)(Klo + (size_t)(l0 + row) * HID + cb + col);
        *(v8u*)&Hs[row * 264 + col] = hv;
        *(v8u*)&Ls[row * 264 + col] = lv;
    }
    __syncthreads();
    const int wm = wave * 16;
    v4f acc[4];
#pragma unroll
    for (int nt = 0; nt < 4; ++nt) { v4f z = {0.f, 0.f, 0.f, 0.f}; acc[nt] = z; }
#pragma unroll
    for (int ks = 0; ks < 8; ++ks) {
        v8s ah = *(const v8s*)&Hs[(wm + l16) * 264 + ks * 32 + quad * 8];
        v8s al = *(const v8s*)&Ls[(wm + l16) * 264 + ks * 32 + quad * 8];
#pragma unroll
        for (int nt = 0; nt < 4; ++nt) {
            v8s bh = *(const v8s*)&Hs[(nt * 16 + l16) * 264 + ks * 32 + quad * 8];
            v8s bl = *(const v8s*)&Ls[(nt * 16 + l16) * 264 + ks * 32 + quad * 8];
            acc[nt] = __builtin_amdgcn_mfma_f32_16x16x32_bf16(ah, bh, acc[nt], 0, 0, 0);
            acc[nt] = __builtin_amdgcn_mfma_f32_16x16x32_bf16(ah, bl, acc[nt], 0, 0, 0);
            acc[nt] = __builtin_amdgcn_mfma_f32_16x16x32_bf16(al, bh, acc[nt], 0, 0, 0);
        }
    }
    float* og = Gg + ((size_t)chunk * 4 + h) * 4096;
#pragma unroll
    for (int nt = 0; nt < 4; ++nt)
#pragma unroll
        for (int r = 0; r < 4; ++r)
            og[(wm + quad * 4 + r) * 64 + nt * 16 + l16] = acc[nt][r];
}

// ---------------- T recurrence per chunk via nilpotent doubling + MFMA ----------------
// T_final = 3*(I-A)^{-1} - 2I, A = -tril(beta*gram, -1); (I-A)^{-1} = prod (I + A^(2^k)).
__global__ __launch_bounds__(256) void trec_kernel(const float* __restrict__ Gg,
                                                   const float* __restrict__ betaB,
                                                   float* __restrict__ Tg) {
    const int chunk = blockIdx.x;
    const int tid = threadIdx.x;
    const int wave = tid >> 6, lane = tid & 63;
    const int quad = lane >> 4, l16 = lane & 15;
    const int wm = wave * 16;
    __shared__ unsigned short BhR[64 * 72], BlR[64 * 72];  // B rows   [i][j]
    __shared__ unsigned short BhT[64 * 72], BlT[64 * 72];  // B^T rows [j][i]
    __shared__ unsigned short PhR[64 * 72], PlR[64 * 72];  // P rows   [i][j]
    __shared__ float Pf[64 * 73];                          // P master copy (f32)
    __shared__ float betS[256];
    betS[tid] = betaB[(size_t)chunk * 256 + tid];
    __syncthreads();
    const float* gg = Gg + (size_t)chunk * 4 * 4096;
#pragma unroll
    for (int s = 0; s < 16; ++s) {
        int idx = tid + 256 * s;
        int i = idx >> 6, j = idx & 63;
        float a = 0.f;
        if (i > j) {
            a = -(betS[i * 4 + 0] * gg[idx] + betS[i * 4 + 1] * gg[4096 + idx] +
                  betS[i * 4 + 2] * gg[2 * 4096 + idx] + betS[i * 4 + 3] * gg[3 * 4096 + idx]);
        }
        unsigned short ah = f2bu(a);
        unsigned short al = f2bu(a - bu2f(ah));
        BhR[i * 72 + j] = ah;
        BlR[i * 72 + j] = al;
        BhT[j * 72 + i] = ah;
        BlT[j * 72 + i] = al;
        float p = (i == j) ? 1.f : 0.f;
        Pf[i * 73 + j] = p;
        PhR[i * 72 + j] = f2bu(p);
        PlR[i * 72 + j] = 0;
    }
    __syncthreads();

    for (int st = 0; st < 6; ++st) {
        v8s aBh[2], aBl[2], aPh[2], aPl[2];
        v8s bTh[2][4], bTl[2][4];
#pragma unroll
        for (int kk = 0; kk < 2; ++kk) {
            aBh[kk] = *(const v8s*)&BhR[(wm + l16) * 72 + kk * 32 + quad * 8];
            aBl[kk] = *(const v8s*)&BlR[(wm + l16) * 72 + kk * 32 + quad * 8];
            aPh[kk] = *(const v8s*)&PhR[(wm + l16) * 72 + kk * 32 + quad * 8];
            aPl[kk] = *(const v8s*)&PlR[(wm + l16) * 72 + kk * 32 + quad * 8];
#pragma unroll
            for (int nt = 0; nt < 4; ++nt) {
                bTh[kk][nt] = *(const v8s*)&BhT[(nt * 16 + l16) * 72 + kk * 32 + quad * 8];
                bTl[kk][nt] = *(const v8s*)&BlT[(nt * 16 + l16) * 72 + kk * 32 + quad * 8];
            }
        }
        v4f accP[4], accB[4];
#pragma unroll
        for (int nt = 0; nt < 4; ++nt) {
#pragma unroll
            for (int r = 0; r < 4; ++r)
                accP[nt][r] = Pf[(wm + quad * 4 + r) * 73 + nt * 16 + l16];
            v4f z = {0.f, 0.f, 0.f, 0.f};
            accB[nt] = z;
        }
        __syncthreads();  // all reads done before anyone writes
#pragma unroll
        for (int kk = 0; kk < 2; ++kk)
#pragma unroll
            for (int nt = 0; nt < 4; ++nt) {
                accP[nt] = __builtin_amdgcn_mfma_f32_16x16x32_bf16(aPh[kk], bTh[kk][nt], accP[nt], 0, 0, 0);
                accP[nt] = __builtin_amdgcn_mfma_f32_16x16x32_bf16(aPh[kk], bTl[kk][nt], accP[nt], 0, 0, 0);
                accP[nt] = __builtin_amdgcn_mfma_f32_16x16x32_bf16(aPl[kk], bTh[kk][nt], accP[nt], 0, 0, 0);
            }
        if (st < 5) {
#pragma unroll
            for (int kk = 0; kk < 2; ++kk)
#pragma unroll
                for (int nt = 0; nt < 4; ++nt) {
                    accB[nt] = __builtin_amdgcn_mfma_f32_16x16x32_bf16(aBh[kk], bTh[kk][nt], accB[nt], 0, 0, 0);
                    accB[nt] = __builtin_amdgcn_mfma_f32_16x16x32_bf16(aBh[kk], bTl[kk][nt], accB[nt], 0, 0, 0);
                    accB[nt] = __builtin_amdgcn_mfma_f32_16x16x32_bf16(aBl[kk], bTh[kk][nt], accB[nt], 0, 0, 0);
                }
        }
#pragma unroll
        for (int nt = 0; nt < 4; ++nt)
#pragma unroll
            for (int r = 0; r < 4; ++r) {
                int row = wm + quad * 4 + r;
                int col = nt * 16 + l16;
                float pv = accP[nt][r];
                Pf[row * 73 + col] = pv;
                unsigned short ph = f2bu(pv);
                PhR[row * 72 + col] = ph;
                PlR[row * 72 + col] = f2bu(pv - bu2f(ph));
                if (st < 5) {
                    float bv = accB[nt][r];
                    unsigned short bh2 = f2bu(bv);
                    unsigned short bl2 = f2bu(bv - bu2f(bh2));
                    BhR[row * 72 + col] = bh2;
                    BlR[row * 72 + col] = bl2;
                    BhT[col * 72 + row] = bh2;
                    BlT[col * 72 + row] = bl2;
                }
            }
        __syncthreads();
    }
#pragma unroll
    for (int s = 0; s < 16; ++s) {
        int idx = tid + 256 * s;
        int i = idx >> 6, j = idx & 63;
        float t = (i == j) ? 1.f : 3.f * Pf[i * 73 + j];
        Tg[(size_t)chunk * 4096 + idx] = t;
    }
}

// ---------------- W = T'·K, U = T'·V via MFMA (T' = T·diag(beta)); fused kw/ku ----------------
// round-6 staged form (shared Th/Tl LDS staging — 4 waves share one conversion pass).
// Staging vectorized: thread owns 16 consecutive j of one row -> coalesced 64B Tg read,
// 4x ds_write_b128 (2-way bank aliasing = free). Bit-identical values.
__global__ __launch_bounds__(256) void wu_mfma_kernel(const float* __restrict__ Tg,
                                                      const unsigned short* __restrict__ Khi,
                                                      const unsigned short* __restrict__ Vhi,
                                                      const float* __restrict__ betaB,
                                                      unsigned short* __restrict__ Wb,
                                                      unsigned short* __restrict__ Ub,
                                                      float* __restrict__ kw, float* __restrict__ ku) {
    const int chunk = blockIdx.x;  // 128
    const int h = blockIdx.y;      // 4
    const int half = blockIdx.z;   // 2
    const int tid = threadIdx.x;
    const int wave = tid >> 6, lane = tid & 63;
    const int quad = lane >> 4, l16 = lane & 15;
    const size_t l0 = (size_t)chunk * 64;
    const int f0 = h * 256 + half * 128;
    __shared__ unsigned short Th[64 * 72], Tl[64 * 72];
    __shared__ unsigned short KT[128 * 72], VT[128 * 72];
    __shared__ float betS[64];
    if (tid < 64) betS[tid] = betaB[(l0 + tid) * 4 + h];
    __syncthreads();
    {
        const int c = tid >> 2;          // T' row 0..63
        const int j0 = (tid & 3) * 16;   // 16 consecutive cols
        const float* trow = Tg + (size_t)chunk * 4096 + (size_t)c * 64 + j0;
        v8u h0, h1, l0v, l1v;
#pragma unroll
        for (int i = 0; i < 8; ++i) {
            float v = trow[i] * betS[j0 + i];
            unsigned short hv = f2bu(v);
            h0[i] = hv;
            l0v[i] = f2bu(v - bu2f(hv));
        }
#pragma unroll
        for (int i = 0; i < 8; ++i) {
            float v = trow[8 + i] * betS[j0 + 8 + i];
            unsigned short hv = f2bu(v);
            h1[i] = hv;
            l1v[i] = f2bu(v - bu2f(hv));
        }
        *(v8u*)&Th[c * 72 + j0] = h0;
        *(v8u*)&Th[c * 72 + j0 + 8] = h1;
        *(v8u*)&Tl[c * 72 + j0] = l0v;
        *(v8u*)&Tl[c * 72 + j0 + 8] = l1v;
    }
#pragma unroll
    for (int pass = 0; pass < 4; ++pass) {
        int j = pass * 16 + (tid >> 4);
        int fc = (tid & 15) * 8;
        v8u kv = *(const v8u*)(Khi + (l0 + j) * HID + f0 + fc);
        v8u vv = *(const v8u*)(Vhi + (l0 + j) * HID + f0 + fc);
#pragma unroll
        for (int i = 0; i < 8; ++i) {
            KT[(fc + i) * 72 + j] = kv[i];
            VT[(fc + i) * 72 + j] = vv[i];
        }
    }
    __syncthreads();

    const int nf = wave * 32;
    const int bb = chunk >> 6, nn = chunk & 63;
    const size_t obase = (((size_t)bb * 4 + h) * 64 + nn) * 256 + half * 128;

#pragma unroll
    for (int phase = 0; phase < 2; ++phase) {
        const unsigned short* BT = phase ? VT : KT;
        v4f acc[4][2];
#pragma unroll
        for (int mt = 0; mt < 4; ++mt)
#pragma unroll
            for (int nt = 0; nt < 2; ++nt) { v4f z = {0.f, 0.f, 0.f, 0.f}; acc[mt][nt] = z; }
#pragma unroll
        for (int k0 = 0; k0 < 64; k0 += 32) {
            v8s ah[4], al[4], bf[2];
#pragma unroll
            for (int mt = 0; mt < 4; ++mt) {
                ah[mt] = *(const v8s*)&Th[(mt * 16 + l16) * 72 + k0 + quad * 8];
                al[mt] = *(const v8s*)&Tl[(mt * 16 + l16) * 72 + k0 + quad * 8];
            }
#pragma unroll
            for (int nt = 0; nt < 2; ++nt)
                bf[nt] = *(const v8s*)&BT[(nf + nt * 16 + l16) * 72 + k0 + quad * 8];
#pragma unroll
            for (int mt = 0; mt < 4; ++mt)
#pragma unroll
                for (int nt = 0; nt < 2; ++nt) {
                    acc[mt][nt] = __builtin_amdgcn_mfma_f32_16x16x32_bf16(ah[mt], bf[nt], acc[mt][nt], 0, 0, 0);
                    acc[mt][nt] = __builtin_amdgcn_mfma_f32_16x16x32_bf16(al[mt], bf[nt], acc[mt][nt], 0, 0, 0);
                }
        }
        unsigned short* Out = phase ? Ub : Wb;
        float* kk = phase ? ku : kw;
#pragma unroll
        for (int nt = 0; nt < 2; ++nt) {
            const int fl = nf + nt * 16 + l16;
            float dot = 0.f;
#pragma unroll
            for (int mt = 0; mt < 4; ++mt)
#pragma unroll
                for (int r = 0; r < 4; ++r) {
                    const int c = mt * 16 + quad * 4 + r;
                    float wv = acc[mt][nt][r];
                    Out[(l0 + c) * HID + f0 + fl] = f2bu(wv);
                    dot += bu2f(KT[fl * 72 + c]) * wv;
                }
            dot += __shfl_xor(dot, 16);
            dot += __shfl_xor(dot, 32);
            if (quad == 0) kk[obase + fl] = dot;
        }
    }
}

// ---------------- diagonal scan over chunks (load-pipelined serial loop) ----------------
__global__ __launch_bounds__(256) void scan_kernel(const float* __restrict__ kw,
                                                   const float* __restrict__ ku,
                                                   float* __restrict__ dsA) {
    const int bh = blockIdx.x;
    size_t idx = (size_t)bh * 64 * 256 + threadIdx.x;
    float ds = 0.f;
    float kwc = kw[idx], kuc = ku[idx];
    for (int n = 0; n < 64; ++n) {
        float kwn = 0.f, kun = 0.f;
        if (n < 63) {  // prefetch next chunk's coeffs off the dependent chain
            kwn = kw[idx + 256];
            kun = ku[idx + 256];
        }
        dsA[idx] = ds;
        ds = ds * (1.f - kwc) + kuc;
        kwc = kwn;
        kuc = kun;
        idx += 256;
    }
}

// ---------------- o = q*ds + [c<=b]*A*(u - w*ds); fused RMSNorm + bf16 cast (wave-per-row) ----------------
__global__ __launch_bounds__(256) void o_kernel(const unsigned short* __restrict__ Qb,
                                                const unsigned short* __restrict__ Khi,
                                                const unsigned short* __restrict__ Wb,
                                                const unsigned short* __restrict__ Ub,
                                                const float* __restrict__ dsA,
                                                const float* __restrict__ rmsw,
                                                unsigned short* __restrict__ ob,
                                                unsigned short* __restrict__ ub) {
    const int r = blockIdx.x * 4 + (threadIdx.x >> 6);
    const int lane = threadIdx.x & 63;
    const int b = r >> 12, l = r & (L_SEQ - 1);
    const int n = l >> 6, cpos = l & 63;
    const size_t rowb = (size_t)r * HID;
    const bool doA = (cpos <= b);
    float qv[4][4];
    v4f dsv[4];
    float As = 0.f;
#pragma unroll
    for (int hh = 0; hh < 4; ++hh) {
        const int c4 = hh * 256 + lane * 4;
        dsv[hh] = *(const v4f*)&dsA[(((size_t)b * 4 + hh) * 64 + n) * 256 + lane * 4];
        v4us qu = *(const v4us*)&Qb[rowb + c4];
#pragma unroll
        for (int i = 0; i < 4; ++i) qv[hh][i] = bu2f(qu[i]);
        if (doA) {
            v4us kq = *(const v4us*)&Khi[rowb + c4];
#pragma unroll
            for (int i = 0; i < 4; ++i) As += qv[hh][i] * bu2f(kq[i]);
        }
    }
    float Aval = 0.f;
    if (doA) {
#pragma unroll
        for (int off = 32; off; off >>= 1) As += __shfl_xor(As, off);
        Aval = As;
    }
    float ss = 0.f;
    float ov[4][4];
#pragma unroll
    for (int hh = 0; hh < 4; ++hh) {
        const int c4 = hh * 256 + lane * 4;
        v4us uu = *(const v4us*)&Ub[rowb + c4];
        v4us wu4 = *(const v4us*)&Wb[rowb + c4];
        v4us up;
#pragma unroll
        for (int i = 0; i < 4; ++i) {
            float u = bu2f(uu[i]) - bu2f(wu4[i]) * dsv[hh][i];
            up[i] = f2bu(u);
            float o = qv[hh][i] * dsv[hh][i];
            if (doA) o += Aval * u;
            ov[hh][i] = o;
            ss += o * o;
        }
        *(v4us*)&ub[rowb + c4] = up;
    }
#pragma unroll
    for (int off = 32; off; off >>= 1) ss += __shfl_xor(ss, off);
    float scale = rsqrtf(ss * (1.f / 1024.f) + 1e-5f);
#pragma unroll
    for (int hh = 0; hh < 4; ++hh) {
        const int c4 = hh * 256 + lane * 4;
        v4f rw = *(const v4f*)&rmsw[c4];
        v4us op;
#pragma unroll
        for (int i = 0; i < 4; ++i) op[i] = f2bu(ov[hh][i] * scale * rw[i]);
        *(v4us*)&ob[rowb + c4] = op;
    }
}

// ---------------- state S = K^T u'  via MFMA (n-split partials) ----------------
__global__ __launch_bounds__(256) void s_mfma_kernel(const unsigned short* __restrict__ Khi,
                                                     const unsigned short* __restrict__ Ub,
                                                     float* __restrict__ Spart) {
    const int bh = blockIdx.x;
    const int b = bh >> 2, h = bh & 3;
    const int dt = blockIdx.y;
    const int et = blockIdx.z & 1;
    const int ns = blockIdx.z >> 1;
    const int tid = threadIdx.x;
    const int wave = tid >> 6, lane = tid & 63;
    const int quad = lane >> 4, l16 = lane & 15;
    const int wm = (wave >> 1) * 64, wn = (wave & 1) * 64;
    __shared__ unsigned short Kt[128 * 40];
    __shared__ unsigned short Ut[128 * 40];
    const int cc = tid >> 3;
    const int dcol = (tid & 7) * 16;
    const size_t rowbase = (size_t)b * 4096 + (size_t)ns * 512;
    const int ck = h * 256 + dt * 128;
    const int ce = h * 256 + et * 128;
    v4f acc[4][4];
#pragma unroll
    for (int a = 0; a < 4; ++a)
#pragma unroll
        for (int c2 = 0; c2 < 4; ++c2) { v4f z = {0.f, 0.f, 0.f, 0.f}; acc[a][c2] = z; }

    for (int kt = 0; kt < 16; ++kt) {
        size_t row = rowbase + kt * 32 + cc;
        v8u k0 = *(const v8u*)(Khi + row * HID + ck + dcol);
        v8u k1 = *(const v8u*)(Khi + row * HID + ck + dcol + 8);
        v8u u0 = *(const v8u*)(Ub + row * HID + ce + dcol);
        v8u u1 = *(const v8u*)(Ub + row * HID + ce + dcol + 8);
        __syncthreads();
#pragma unroll
        for (int j = 0; j < 8; ++j) {
            Kt[(dcol + j) * 40 + cc] = k0[j];
            Kt[(dcol + 8 + j) * 40 + cc] = k1[j];
            Ut[(dcol + j) * 40 + cc] = u0[j];
            Ut[(dcol + 8 + j) * 40 + cc] = u1[j];
        }
        __syncthreads();
        v8s af[4], bf[4];
#pragma unroll
        for (int mt = 0; mt < 4; ++mt) af[mt] = *(const v8s*)&Kt[(wm + mt * 16 + l16) * 40 + quad * 8];
#pragma unroll
        for (int nt = 0; nt < 4; ++nt) bf[nt] = *(const v8s*)&Ut[(wn + nt * 16 + l16) * 40 + quad * 8];
#pragma unroll
        for (int mt = 0; mt < 4; ++mt)
#pragma unroll
            for (int nt = 0; nt < 4; ++nt)
                acc[mt][nt] = __builtin_amdgcn_mfma_f32_16x16x32_bf16(af[mt], bf[nt], acc[mt][nt], 0, 0, 0);
    }
    float* out = Spart + (size_t)ns * (8 * 256 * 256);
#pragma unroll
    for (int mt = 0; mt < 4; ++mt)
#pragma unroll
        for (int nt = 0; nt < 4; ++nt) {
            int row = dt * 128 + wm + mt * 16 + quad * 4;
            int col = et * 128 + wn + nt * 16 + l16;
#pragma unroll
            for (int r = 0; r < 4; ++r)
                out[((size_t)bh * 256 + row + r) * 256 + col] = acc[mt][nt][r];
        }
}

extern "C" void kernel_launch(void* const* d_in, const int* in_sizes, int n_in,
                              void* d_out, int out_size, void* d_ws, size_t ws_size,
                              hipStream_t stream) {
    const float* x     = (const float*)d_in[0];
    const float* Wq    = (const float*)d_in[1];
    const float* Wk    = (const float*)d_in[2];
    const float* Wv    = (const float*)d_in[3];
    const float* convq = (const float*)d_in[4];
    const float* convk = (const float*)d_in[5];
    const float* convv = (const float*)d_in[6];
    const float* Wbeta = (const float*)d_in[7];
    const float* rmsw  = (const float*)d_in[8];
    const float* Wo    = (const float*)d_in[9];

    // ---- workspace map (aliases documented) ----
    char* ws = (char*)d_ws;
    size_t off = 0;
    auto alloc = [&](size_t bytes) {
        char* p = ws + off;
        off += (bytes + 255) & ~(size_t)255;
        return (void*)p;
    };
    const size_t MM = (size_t)HID * HID;
    unsigned short* xhi   = (unsigned short*)alloc((size_t)BL_TOT * HID * 2);  // later Qm/ob
    unsigned short* Khi   = (unsigned short*)alloc((size_t)BL_TOT * HID * 2);  // conv_k -> s_mfma
    unsigned short* wbQKV = (unsigned short*)alloc(3 * MM * 2);                // [V|K|Q] packed
    unsigned short* wbO   = (unsigned short*)alloc(MM * 2);
    unsigned short* Vhi   = (unsigned short*)alloc((size_t)BL_TOT * HID * 2);
    unsigned short* Wb16  = (unsigned short*)alloc((size_t)BL_TOT * HID * 2);
    unsigned short* Ub16  = (unsigned short*)alloc((size_t)BL_TOT * HID * 2);
    float* Tg    = (float*)alloc((size_t)128 * 4096 * 4);
    float* betaB = (float*)alloc((size_t)BL_TOT * 4 * 4);
    float* kwB   = (float*)alloc((size_t)8 * 64 * 256 * 4);
    float* kuB   = (float*)alloc((size_t)8 * 64 * 256 * 4);
    float* dsA   = (float*)alloc((size_t)8 * 64 * 256 * 4);
    // Gt last: bf16 GEMM output. big = 8192x3072 (merged QKV) if workspace allows.
    const size_t gt_big = (size_t)BL_TOT * 3 * HID * 2;
    const size_t gt_small = (size_t)BL_TOT * HID * 2;
    // Spart (16 MB f32) aliases Gt; ensure allocation covers it in either path.
    const size_t spart_bytes = (size_t)SNS * 8 * 256 * 256 * 4;
    const bool big = (off + (gt_big > spart_bytes ? gt_big : spart_bytes)) <= ws_size;
    unsigned short* Gt = (unsigned short*)alloc(big ? (gt_big > spart_bytes ? gt_big : spart_bytes)
                                                    : (gt_small > spart_bytes ? gt_small : spart_bytes));

    unsigned short* Qm = xhi;   // xhi dead after (last) x-GEMM
    unsigned short* ob = Qm;    // q dead after o_kernel reads its own row
    float* Spart = (float*)Gt;  // Gt dead after conv

    float* out0 = (float*)d_out;
    float* out1 = out0 + (size_t)BL_TOT * HID;
    // d_out as pre-final scratch (validated only after launch):
    unsigned short* Klo = (unsigned short*)out0;            // bytes 0..16.78M
    unsigned short* ubf = (unsigned short*)out0 + 8388608;  // bytes 16.78M..33.55M
    float* Gg = out0 + (size_t)4400000;                     // gram scratch; dead before o_kernel

    dim3 blk(256);
    dim3 ggrid(BL_TOT / 128, HID / 128);

    // fused weight-cvt + beta (blocks [0,1024) = wcvt, [1024,3072) = beta)
    prep_kernel<<<3072, blk, 0, stream>>>(Wv, Wk, Wq, Wo, wbQKV, wbQKV + MM, wbQKV + 2 * MM, wbO,
                                          x, Wbeta, betaB, xhi);

    if (big) {
        // one QKV GEMM (N=3072, bf16 out) + one merged conv dispatch
        gemm_mfma<unsigned short><<<dim3(BL_TOT / 128, 3 * HID / 128), blk, 0, stream>>>(
            xhi, wbQKV, Gt, BL_TOT, 3 * HID, HID);
        conv_kernel<<<dim3(BL_TOT / 4, 3), blk, 0, stream>>>(Gt, 3 * HID, -1, convq, convk, convv,
                                                             Vhi, Khi, Klo, Qm);
        gram_kernel<<<dim3(128, 4), blk, 0, stream>>>(Khi, Klo, Gg);
        trec_kernel<<<128, blk, 0, stream>>>(Gg, betaB, Tg);
    } else {
        // sequential fallback (Gt reused; Q GEMM last so Qm alias of xhi stays safe)
        gemm_mfma<unsigned short><<<ggrid, blk, 0, stream>>>(xhi, wbQKV, Gt, BL_TOT, HID, HID);
        conv_kernel<<<dim3(BL_TOT / 4, 1), blk, 0, stream>>>(Gt, HID, 0, convq, convk, convv, Vhi, Khi, Klo, Qm);
        gemm_mfma<unsigned short><<<ggrid, blk, 0, stream>>>(xhi, wbQKV + MM, Gt, BL_TOT, HID, HID);
        conv_kernel<<<dim3(BL_TOT / 4, 1), blk, 0, stream>>>(Gt, HID, 1, convq, convk, convv, Vhi, Khi, Klo, Qm);
        gram_kernel<<<dim3(128, 4), blk, 0, stream>>>(Khi, Klo, Gg);
        trec_kernel<<<128, blk, 0, stream>>>(Gg, betaB, Tg);
        gemm_mfma<unsigned short><<<ggrid, blk, 0, stream>>>(xhi, wbQKV + 2 * MM, Gt, BL_TOT, HID, HID);
        conv_kernel<<<dim3(BL_TOT / 4, 1), blk, 0, stream>>>(Gt, HID, 2, convq, convk, convv, Vhi, Khi, Klo, Qm);
    }

    // chunked delta rule
    wu_mfma_kernel<<<dim3(128, 4, 2), blk, 0, stream>>>(Tg, Khi, Vhi, betaB, Wb16, Ub16, kwB, kuB);
    scan_kernel<<<8, blk, 0, stream>>>(kwB, kuB, dsA);
    o_kernel<<<BL_TOT / 4, blk, 0, stream>>>(Qm, Khi, Wb16, Ub16, dsA, rmsw, ob, ubf);
    s_mfma_kernel<<<dim3(8, 2, 2 * SNS), blk, 0, stream>>>(Khi, ubf, Spart);

    // fused final projection (blocks [0,512)) + Spart reduce -> out1 (blocks [512,768))
    final_kernel<<<768, blk, 0, stream>>>(ob, wbO, out0, Spart, out1);
}